// Round 5
// baseline (656.852 us; speedup 1.0000x reference)
//
#include <hip/hip_runtime.h>
#include <math.h>

// SegmentGatingNetwork, MFMA path v3 (LDS-free GEMM1).
// prep: W1,W2 -> 3 truncated-bf16 planes each, in MFMA B-fragment order (d_ws).
// gemm1: A-fragments loaded DIRECTLY from x (row-major == fragment layout), split3
//        in-register, B planes register-prefetched from global. No LDS, no barriers.
//        6 plane-products (hh,hm,mh,hl,lh,mm) -> fp32-equivalent accuracy.
// gate:  1 wave per 16 tokens, full h prefetch, B prefetch distance-1, MFMA logits,
//        in-register top-2 butterfly, softmax, scatter.

#define DM 1024
#define DH 256
#define NE 64
#define BM 64
#define BN 128

// d_ws layout (bytes)
#define W1P_OFF 0                 // 3 planes * 131072 dwords
#define W1P_STRIDE 524288
#define W2P_OFF 1572864           // 3 planes * 8192 dwords
#define W2P_STRIDE 32768
#define H_OFF 1671168             // 16384*256*4

typedef __attribute__((ext_vector_type(8))) short bf16x8;
typedef __attribute__((ext_vector_type(4))) float f32x4;

__device__ __forceinline__ unsigned fbits(float f) { return __float_as_uint(f); }
__device__ __forceinline__ float topf(unsigned u) { return __uint_as_float(u & 0xFFFF0000u); }

// truncated 3-plane split
__device__ __forceinline__ void split3(float v, unsigned& h, unsigned& m, unsigned& l) {
    h = fbits(v);
    float r1 = v - topf(h);
    m = fbits(r1);
    float r2 = r1 - topf(m);
    l = fbits(r2);
}
__device__ __forceinline__ unsigned packpair(unsigned a, unsigned b) {
    return __builtin_amdgcn_perm(b, a, 0x07060302);   // [b.hi16 | a.hi16], 1 VALU op
}
__device__ __forceinline__ bf16x8 as_bf(uint4 u) {
    union { uint4 a; bf16x8 b; } c; c.a = u; return c.b;
}

// convert 8 consecutive fp32 (one A-fragment's lane data) -> 3 plane uint4s
__device__ __forceinline__ void cvt8(float4 a, float4 b, uint4& dh, uint4& dm, uint4& dl) {
    float v[8] = {a.x, a.y, a.z, a.w, b.x, b.y, b.z, b.w};
    unsigned hh[8], mm[8], ll[8];
#pragma unroll
    for (int j = 0; j < 8; j++) split3(v[j], hh[j], mm[j], ll[j]);
    dh = (uint4){packpair(hh[0], hh[1]), packpair(hh[2], hh[3]),
                 packpair(hh[4], hh[5]), packpair(hh[6], hh[7])};
    dm = (uint4){packpair(mm[0], mm[1]), packpair(mm[2], mm[3]),
                 packpair(mm[4], mm[5]), packpair(mm[6], mm[7])};
    dl = (uint4){packpair(ll[0], ll[1]), packpair(ll[2], ll[3]),
                 packpair(ll[4], ll[5]), packpair(ll[6], ll[7])};
}

// product schedule (per-chain order identical to R3/R4 passing kernels)
__constant__ int PA_[6] = {0, 0, 1, 0, 2, 1};
__constant__ int PB_[6] = {0, 1, 0, 2, 0, 1};

// ---------------- prep: weight planes in B-fragment order ----------------
__global__ __launch_bounds__(256)
void prep_planes(const float* __restrict__ W1, const float* __restrict__ W2,
                 char* __restrict__ ws) {
    unsigned* w1p = (unsigned*)(ws + W1P_OFF);
    unsigned* w2p = (unsigned*)(ws + W2P_OFF);
    const int gt = blockIdx.x * 256 + threadIdx.x;
    if (gt < 131072) {
        const int q = gt & 3, L = (gt >> 2) & 63, nt = (gt >> 8) & 15, kc = gt >> 12;
        const int n = nt * 16 + (L & 15);
        const int k0 = kc * 32 + ((L >> 4) & 3) * 8 + 2 * q;
        float v0 = W1[(size_t)k0 * DH + n];
        float v1 = W1[(size_t)(k0 + 1) * DH + n];
        unsigned h0, m0, l0, h1, m1, l1;
        split3(v0, h0, m0, l0);
        split3(v1, h1, m1, l1);
        w1p[0 * 131072 + gt] = packpair(h0, h1);
        w1p[1 * 131072 + gt] = packpair(m0, m1);
        w1p[2 * 131072 + gt] = packpair(l0, l1);
    } else {
        const int g2 = gt - 131072;
        if (g2 < 8192) {
            const int q = g2 & 3, L = (g2 >> 2) & 63, nt = (g2 >> 8) & 3, kc = g2 >> 10;
            const int n = nt * 16 + (L & 15);
            const int k0 = kc * 32 + ((L >> 4) & 3) * 8 + 2 * q;
            float v0 = W2[k0 * NE + n];
            float v1 = W2[(k0 + 1) * NE + n];
            unsigned h0, m0, l0, h1, m1, l1;
            split3(v0, h0, m0, l0);
            split3(v1, h1, m1, l1);
            w2p[0 * 8192 + g2] = packpair(h0, h1);
            w2p[1 * 8192 + g2] = packpair(m0, m1);
            w2p[2 * 8192 + g2] = packpair(l0, l1);
        }
    }
}

// ---------------- GEMM1: h = tanh(x @ W1 + b1) ----------------
// 64 tok x 128 hid per block; wave tile 32 tok (ms=2) x 64 hid (nt=4).
// grid (256, 2), 2 blocks/CU. No LDS.
__global__ __launch_bounds__(256, 2)
void gemm1_mfma(const float* __restrict__ x, const char* __restrict__ w1p,
                const float* __restrict__ b1, float* __restrict__ h) {
    const int tid  = threadIdx.x;
    const int lane = tid & 63;
    const int wave = tid >> 6;
    const int wm   = wave >> 1;
    const int wn   = wave & 1;
    const int t0 = blockIdx.x * BM;
    const int n0 = blockIdx.y * BN;
    const int l15 = lane & 15;
    const int lq  = lane >> 4;

    // A: lane reads x[row(ms)][kc*32 + lq*8 .. +8]  (row-major == fragment layout)
    const float* xp0 = x + (size_t)(t0 + wm * 32 + l15) * DM + lq * 8;        // ms=0
    const float* xp1 = xp0 + (size_t)16 * DM;                                  // ms=1
    // B: fragment base for this wave's 4 nt subtiles
    const char* bt = w1p + (size_t)(blockIdx.y * 8 + wn * 4) * 1024 + lane * 16;

    f32x4 acc[2][4];
#pragma unroll
    for (int i = 0; i < 2; i++)
#pragma unroll
        for (int j = 0; j < 4; j++) acc[i][j] = (f32x4){0.f, 0.f, 0.f, 0.f};

    // prologue: kc=0 loads
    float4 xc[2][2];
    xc[0][0] = *(const float4*)(xp0);
    xc[0][1] = *(const float4*)(xp0 + 4);
    xc[1][0] = *(const float4*)(xp1);
    xc[1][1] = *(const float4*)(xp1 + 4);
    uint4 bc[3][4];
#pragma unroll
    for (int p = 0; p < 3; p++)
#pragma unroll
        for (int nt = 0; nt < 4; nt++)
            bc[p][nt] = *(const uint4*)(bt + p * W1P_STRIDE + nt * 1024);

    for (int kc = 0; kc < 32; kc++) {
        const bool pre = (kc + 1) < 32;
        float4 xn[2][2];
        uint4 bn[3][4];
        if (pre) {
            const int ko = (kc + 1) * 32;
            xn[0][0] = *(const float4*)(xp0 + ko);
            xn[0][1] = *(const float4*)(xp0 + ko + 4);
            xn[1][0] = *(const float4*)(xp1 + ko);
            xn[1][1] = *(const float4*)(xp1 + ko + 4);
#pragma unroll
            for (int p = 0; p < 3; p++)
#pragma unroll
                for (int nt = 0; nt < 4; nt++)
                    bn[p][nt] = *(const uint4*)(bt + p * W1P_STRIDE + (size_t)((kc + 1) * 16 + nt) * 1024);
        }

        // convert current A in-register
        uint4 au[3][2];
#pragma unroll
        for (int ms = 0; ms < 2; ms++)
            cvt8(xc[ms][0], xc[ms][1], au[0][ms], au[1][ms], au[2][ms]);

        // MFMA, product-major: 8 independent acc chains between dependent steps
#pragma unroll
        for (int s = 0; s < 6; s++) {
            const int pa = PA_[s], pb = PB_[s];
#pragma unroll
            for (int ms = 0; ms < 2; ms++)
#pragma unroll
                for (int nt = 0; nt < 4; nt++)
                    acc[ms][nt] = __builtin_amdgcn_mfma_f32_16x16x32_bf16(
                        as_bf(au[pa][ms]), as_bf(bc[pb][nt]), acc[ms][nt], 0, 0, 0);
        }

        if (pre) {
#pragma unroll
            for (int ms = 0; ms < 2; ms++) {
                xc[ms][0] = xn[ms][0];
                xc[ms][1] = xn[ms][1];
            }
#pragma unroll
            for (int p = 0; p < 3; p++)
#pragma unroll
                for (int nt = 0; nt < 4; nt++) bc[p][nt] = bn[p][nt];
        }
    }

    // epilogue: bias + tanh -> h (C/D: col = lane&15, row = (lane>>4)*4 + reg)
#pragma unroll
    for (int nt = 0; nt < 4; nt++) {
        const int hid = n0 + (wn * 4 + nt) * 16 + l15;
        const float bias = b1[hid];
#pragma unroll
        for (int ms = 0; ms < 2; ms++) {
            const int tokb = t0 + wm * 32 + ms * 16 + lq * 4;
#pragma unroll
            for (int r = 0; r < 4; r++)
                h[(size_t)(tokb + r) * DH + hid] = tanhf(acc[ms][nt][r] + bias);
        }
    }
}

// ---------------- gate: logits = h @ W2 + b2, top-2 softmax scatter ----------------
// 1 wave per 16 tokens; full h prefetch; B prefetch distance-1. grid = T/16, 64 thr.
__global__ __launch_bounds__(64)
void gate_kernel(const float* __restrict__ h, const char* __restrict__ w2p,
                 const float* __restrict__ b2, float* __restrict__ gates,
                 float* __restrict__ logits_out) {
    const int lane = threadIdx.x & 63;
    const int l15 = lane & 15;
    const int lq = lane >> 4;
    const int tok16 = blockIdx.x * 16;

    const float* hb = h + (size_t)(tok16 + l15) * DH + lq * 8;
    const char* bt = w2p + lane * 16;

    // full h prefetch: 16 dwordx4
    float4 hv[16];
#pragma unroll
    for (int kc = 0; kc < 8; kc++) {
        hv[2 * kc]     = *(const float4*)(hb + kc * 32);
        hv[2 * kc + 1] = *(const float4*)(hb + kc * 32 + 4);
    }

    uint4 bc[3][4];
#pragma unroll
    for (int p = 0; p < 3; p++)
#pragma unroll
        for (int nt = 0; nt < 4; nt++)
            bc[p][nt] = *(const uint4*)(bt + p * W2P_STRIDE + nt * 1024);

    f32x4 acc[4];
#pragma unroll
    for (int nt = 0; nt < 4; nt++) acc[nt] = (f32x4){0.f, 0.f, 0.f, 0.f};

#pragma unroll
    for (int kc = 0; kc < 8; kc++) {
        uint4 bn[3][4];
        if (kc + 1 < 8) {
#pragma unroll
            for (int p = 0; p < 3; p++)
#pragma unroll
                for (int nt = 0; nt < 4; nt++)
                    bn[p][nt] = *(const uint4*)(bt + p * W2P_STRIDE + (size_t)((kc + 1) * 4 + nt) * 1024);
        }

        uint4 au[3];
        cvt8(hv[2 * kc], hv[2 * kc + 1], au[0], au[1], au[2]);

#pragma unroll
        for (int s = 0; s < 6; s++) {
            const int pa = PA_[s], pb = PB_[s];
#pragma unroll
            for (int nt = 0; nt < 4; nt++)
                acc[nt] = __builtin_amdgcn_mfma_f32_16x16x32_bf16(
                    as_bf(au[pa]), as_bf(bc[pb][nt]), acc[nt], 0, 0, 0);
        }

        if (kc + 1 < 8) {
#pragma unroll
            for (int p = 0; p < 3; p++)
#pragma unroll
                for (int nt = 0; nt < 4; nt++) bc[p][nt] = bn[p][nt];
        }
    }

    float b2v[4];
#pragma unroll
    for (int nt = 0; nt < 4; nt++) b2v[nt] = b2[nt * 16 + l15];

    // per r: lane holds 4 experts of token tok16 + lq*4 + r
#pragma unroll
    for (int r = 0; r < 4; r++) {
        float v[4]; int e[4];
#pragma unroll
        for (int nt = 0; nt < 4; nt++) { v[nt] = acc[nt][r] + b2v[nt]; e[nt] = nt * 16 + l15; }

        float a1 = v[0], a2 = v[1]; int j1 = e[0], j2 = e[1];
        if (v[1] > v[0]) { a1 = v[1]; j1 = e[1]; a2 = v[0]; j2 = e[0]; }
#pragma unroll
        for (int t = 2; t < 4; t++) {
            if (v[t] > a1) { a2 = a1; j2 = j1; a1 = v[t]; j1 = e[t]; }
            else if (v[t] > a2) { a2 = v[t]; j2 = e[t]; }
        }
#pragma unroll
        for (int off = 1; off < 16; off <<= 1) {
            float ob1 = __shfl_xor(a1, off, 64); int oj1 = __shfl_xor(j1, off, 64);
            float ob2 = __shfl_xor(a2, off, 64); int oj2 = __shfl_xor(j2, off, 64);
            bool bw = (ob1 > a1) || (ob1 == a1 && oj1 < j1);
            float w1v = bw ? ob1 : a1; int w1i = bw ? oj1 : j1;
            float lv = bw ? a1 : ob1;  int li  = bw ? j1 : oj1;
            float rv = bw ? ob2 : a2;  int ri  = bw ? oj2 : j2;
            bool cw = (lv > rv) || (lv == rv && li < ri);
            a1 = w1v; j1 = w1i;
            a2 = cw ? lv : rv; j2 = cw ? li : ri;
        }
        float ex = __expf(a2 - a1);
        float inv = 1.f / (1.f + ex);
        float g1 = inv, g2 = ex * inv;

        const size_t row = (size_t)(tok16 + lq * 4 + r) * NE;
#pragma unroll
        for (int nt = 0; nt < 4; nt++) {
            float gv = (e[nt] == j1) ? g1 : ((e[nt] == j2) ? g2 : 0.f);
            gates[row + e[nt]] = gv;
            logits_out[row + e[nt]] = v[nt];
        }
    }
}

extern "C" void kernel_launch(void* const* d_in, const int* in_sizes, int n_in,
                              void* d_out, int out_size, void* d_ws, size_t ws_size,
                              hipStream_t stream) {
    const float* x  = (const float*)d_in[0];
    const float* W1 = (const float*)d_in[1];
    const float* b1 = (const float*)d_in[2];
    const float* W2 = (const float*)d_in[3];
    const float* b2 = (const float*)d_in[4];

    const int T = in_sizes[0] / DM;   // 16384
    char* ws = (char*)d_ws;
    float* hbuf = (float*)(ws + H_OFF);
    float* gates  = (float*)d_out;
    float* logits = (float*)d_out + (size_t)T * NE;

    prep_planes<<<(131072 + 8192) / 256, 256, 0, stream>>>(W1, W2, ws);
    gemm1_mfma<<<dim3(T / BM, 2), 256, 0, stream>>>(x, ws + W1P_OFF, b1, hbuf);
    gate_kernel<<<T / 16, 64, 0, stream>>>(hbuf, ws + W2P_OFF, b2, gates, logits);
}

// Round 6
// 179.753 us; speedup vs baseline: 3.6542x; 3.6542x over previous
//
#include <hip/hip_runtime.h>
#include <math.h>

// SegmentGatingNetwork, MFMA path v4 (LDS-free GEMM1, spill-fixed).
// R5 bug: __constant__ product-schedule tables -> dynamic indexing of private arrays
// -> everything spilled to scratch (VGPR=44, 2.6GB scratch traffic). Fixed with a
// compile-time literal product sequence (macro) + explicit ping-pong prefetch buffers.
// prep: W1,W2 -> 3 truncated-bf16 planes each, in MFMA B-fragment order (d_ws).
// gemm1: A-fragments loaded DIRECTLY from x (row-major == fragment layout), split3
//        in-register, B planes register-prefetched from global. No LDS, no barriers.
//        6 plane-products (hh,hm,mh,hl,lh,mm) -> fp32-equivalent accuracy.
// gate:  1 wave per 16 tokens, full h prefetch, B prefetch distance-1, MFMA logits,
//        in-register top-2 butterfly, softmax, scatter.

#define DM 1024
#define DH 256
#define NE 64
#define BM 64
#define BN 128

// d_ws layout (bytes)
#define W1P_OFF 0                 // 3 planes * 131072 dwords
#define W1P_STRIDE 524288
#define W2P_OFF 1572864           // 3 planes * 8192 dwords
#define W2P_STRIDE 32768
#define H_OFF 1671168             // 16384*256*4

typedef __attribute__((ext_vector_type(8))) short bf16x8;
typedef __attribute__((ext_vector_type(4))) float f32x4;

__device__ __forceinline__ unsigned fbits(float f) { return __float_as_uint(f); }
__device__ __forceinline__ float topf(unsigned u) { return __uint_as_float(u & 0xFFFF0000u); }

// truncated 3-plane split
__device__ __forceinline__ void split3(float v, unsigned& h, unsigned& m, unsigned& l) {
    h = fbits(v);
    float r1 = v - topf(h);
    m = fbits(r1);
    float r2 = r1 - topf(m);
    l = fbits(r2);
}
__device__ __forceinline__ unsigned packpair(unsigned a, unsigned b) {
    return __builtin_amdgcn_perm(b, a, 0x07060302);   // [b.hi16 | a.hi16], 1 VALU op
}
__device__ __forceinline__ bf16x8 as_bf(uint4 u) {
    union { uint4 a; bf16x8 b; } c; c.a = u; return c.b;
}

// convert 8 consecutive fp32 (one A-fragment's lane data) -> 3 plane uint4s
__device__ __forceinline__ void cvt8(float4 a, float4 b, uint4& dh, uint4& dm, uint4& dl) {
    float v[8] = {a.x, a.y, a.z, a.w, b.x, b.y, b.z, b.w};
    unsigned hh[8], mm[8], ll[8];
#pragma unroll
    for (int j = 0; j < 8; j++) split3(v[j], hh[j], mm[j], ll[j]);
    dh = (uint4){packpair(hh[0], hh[1]), packpair(hh[2], hh[3]),
                 packpair(hh[4], hh[5]), packpair(hh[6], hh[7])};
    dm = (uint4){packpair(mm[0], mm[1]), packpair(mm[2], mm[3]),
                 packpair(mm[4], mm[5]), packpair(mm[6], mm[7])};
    dl = (uint4){packpair(ll[0], ll[1]), packpair(ll[2], ll[3]),
                 packpair(ll[4], ll[5]), packpair(ll[6], ll[7])};
}

// product schedule: (pa,pb) = hh, hm, mh, hl, lh, mm — LITERAL indices (compile-time)
#define PROD_SEQ(STEP) STEP(0,0) STEP(0,1) STEP(1,0) STEP(0,2) STEP(2,0) STEP(1,1)

// ---------------- prep: weight planes in B-fragment order ----------------
// Fragment conventions (verified by R3/R4 passing):
//   A/B-frag 16x16x32: m/n = lane&15, k = (lane>>4)*8 + j, dword q = k-pair (2q,2q+1)
//   C/D: col(n) = lane&15, row(m) = (lane>>4)*4 + reg
__global__ __launch_bounds__(256)
void prep_planes(const float* __restrict__ W1, const float* __restrict__ W2,
                 char* __restrict__ ws) {
    unsigned* w1p = (unsigned*)(ws + W1P_OFF);
    unsigned* w2p = (unsigned*)(ws + W2P_OFF);
    const int gt = blockIdx.x * 256 + threadIdx.x;
    if (gt < 131072) {
        const int q = gt & 3, L = (gt >> 2) & 63, nt = (gt >> 8) & 15, kc = gt >> 12;
        const int n = nt * 16 + (L & 15);
        const int k0 = kc * 32 + ((L >> 4) & 3) * 8 + 2 * q;
        float v0 = W1[(size_t)k0 * DH + n];
        float v1 = W1[(size_t)(k0 + 1) * DH + n];
        unsigned h0, m0, l0, h1, m1, l1;
        split3(v0, h0, m0, l0);
        split3(v1, h1, m1, l1);
        w1p[0 * 131072 + gt] = packpair(h0, h1);
        w1p[1 * 131072 + gt] = packpair(m0, m1);
        w1p[2 * 131072 + gt] = packpair(l0, l1);
    } else {
        const int g2 = gt - 131072;
        if (g2 < 8192) {
            const int q = g2 & 3, L = (g2 >> 2) & 63, nt = (g2 >> 8) & 3, kc = g2 >> 10;
            const int n = nt * 16 + (L & 15);
            const int k0 = kc * 32 + ((L >> 4) & 3) * 8 + 2 * q;
            float v0 = W2[k0 * NE + n];
            float v1 = W2[(k0 + 1) * NE + n];
            unsigned h0, m0, l0, h1, m1, l1;
            split3(v0, h0, m0, l0);
            split3(v1, h1, m1, l1);
            w2p[0 * 8192 + g2] = packpair(h0, h1);
            w2p[1 * 8192 + g2] = packpair(m0, m1);
            w2p[2 * 8192 + g2] = packpair(l0, l1);
        }
    }
}

// ---------------- GEMM1 helpers ----------------
__device__ __forceinline__ void g1_load(const float* xp0, const float* xp1, const char* bt,
                                        int kc, float4 (&xc)[2][2], uint4 (&bc)[3][4]) {
    const int ko = kc * 32;
    xc[0][0] = *(const float4*)(xp0 + ko);
    xc[0][1] = *(const float4*)(xp0 + ko + 4);
    xc[1][0] = *(const float4*)(xp1 + ko);
    xc[1][1] = *(const float4*)(xp1 + ko + 4);
#pragma unroll
    for (int p = 0; p < 3; p++)
#pragma unroll
        for (int nt = 0; nt < 4; nt++)
            bc[p][nt] = *(const uint4*)(bt + p * W1P_STRIDE + (size_t)(kc * 16 + nt) * 1024);
}

__device__ __forceinline__ void g1_compute(float4 (&xc)[2][2], uint4 (&bc)[3][4],
                                           f32x4 (&acc)[2][4]) {
    uint4 au[3][2];
#pragma unroll
    for (int ms = 0; ms < 2; ms++)
        cvt8(xc[ms][0], xc[ms][1], au[0][ms], au[1][ms], au[2][ms]);
#define G1_STEP(pa, pb)                                                         \
    {                                                                           \
        _Pragma("unroll")                                                       \
        for (int ms = 0; ms < 2; ms++)                                          \
            _Pragma("unroll")                                                   \
            for (int nt = 0; nt < 4; nt++)                                      \
                acc[ms][nt] = __builtin_amdgcn_mfma_f32_16x16x32_bf16(          \
                    as_bf(au[pa][ms]), as_bf(bc[pb][nt]), acc[ms][nt], 0, 0, 0);\
    }
    PROD_SEQ(G1_STEP)
#undef G1_STEP
}

// ---------------- GEMM1: h = tanh(x @ W1 + b1) ----------------
// 64 tok x 128 hid per block; wave tile 32 tok (ms=2) x 64 hid (nt=4).
// grid (256, 2), 2 blocks/CU. No LDS, no barriers.
__global__ __launch_bounds__(256, 2)
void gemm1_mfma(const float* __restrict__ x, const char* __restrict__ w1p,
                const float* __restrict__ b1, float* __restrict__ h) {
    const int tid  = threadIdx.x;
    const int lane = tid & 63;
    const int wave = tid >> 6;
    const int wm   = wave >> 1;
    const int wn   = wave & 1;
    const int t0 = blockIdx.x * BM;
    const int n0 = blockIdx.y * BN;
    const int l15 = lane & 15;
    const int lq  = lane >> 4;

    // A: lane reads x[row(ms)][kc*32 + lq*8 .. +8]  (row-major == fragment layout)
    const float* xp0 = x + (size_t)(t0 + wm * 32 + l15) * DM + lq * 8;   // ms=0
    const float* xp1 = xp0 + (size_t)16 * DM;                             // ms=1
    // B: fragment base for this wave's 4 nt subtiles
    const char* bt = w1p + (size_t)(blockIdx.y * 8 + wn * 4) * 1024 + lane * 16;

    f32x4 acc[2][4];
#pragma unroll
    for (int i = 0; i < 2; i++)
#pragma unroll
        for (int j = 0; j < 4; j++) acc[i][j] = (f32x4){0.f, 0.f, 0.f, 0.f};

    float4 x0[2][2], x1[2][2];
    uint4 b0[3][4], b1buf[3][4];

    g1_load(xp0, xp1, bt, 0, x0, b0);

    // ping-pong, 2 chunks per iteration: no dynamic buffer index, no reg-copy chains
    for (int kc2 = 0; kc2 < 16; kc2++) {
        const int kc = kc2 * 2;
        g1_load(xp0, xp1, bt, kc + 1, x1, b1buf);
        g1_compute(x0, b0, acc);
        if (kc + 2 < 32) g1_load(xp0, xp1, bt, kc + 2, x0, b0);
        g1_compute(x1, b1buf, acc);
    }

    // epilogue: bias + tanh -> h (C/D: col = lane&15, row = (lane>>4)*4 + reg)
#pragma unroll
    for (int nt = 0; nt < 4; nt++) {
        const int hid = n0 + (wn * 4 + nt) * 16 + l15;
        const float bias = b1[hid];
#pragma unroll
        for (int ms = 0; ms < 2; ms++) {
            const int tokb = t0 + wm * 32 + ms * 16 + lq * 4;
#pragma unroll
            for (int r = 0; r < 4; r++)
                h[(size_t)(tokb + r) * DH + hid] = tanhf(acc[ms][nt][r] + bias);
        }
    }
}

// ---------------- gate: logits = h @ W2 + b2, top-2 softmax scatter ----------------
// 1 wave per 16 tokens; full h prefetch; B prefetch distance-1. grid = T/16, 64 thr.
__global__ __launch_bounds__(64)
void gate_kernel(const float* __restrict__ h, const char* __restrict__ w2p,
                 const float* __restrict__ b2, float* __restrict__ gates,
                 float* __restrict__ logits_out) {
    const int lane = threadIdx.x & 63;
    const int l15 = lane & 15;
    const int lq = lane >> 4;
    const int tok16 = blockIdx.x * 16;

    const float* hb = h + (size_t)(tok16 + l15) * DH + lq * 8;
    const char* bt = w2p + lane * 16;

    // full h prefetch: 16 dwordx4
    float4 hv[16];
#pragma unroll
    for (int kc = 0; kc < 8; kc++) {
        hv[2 * kc]     = *(const float4*)(hb + kc * 32);
        hv[2 * kc + 1] = *(const float4*)(hb + kc * 32 + 4);
    }

    uint4 bc[3][4], bn[3][4];
#pragma unroll
    for (int p = 0; p < 3; p++)
#pragma unroll
        for (int nt = 0; nt < 4; nt++)
            bc[p][nt] = *(const uint4*)(bt + p * W2P_STRIDE + nt * 1024);

    f32x4 acc[4];
#pragma unroll
    for (int nt = 0; nt < 4; nt++) acc[nt] = (f32x4){0.f, 0.f, 0.f, 0.f};

#pragma unroll
    for (int kc = 0; kc < 8; kc++) {
        if (kc + 1 < 8) {
#pragma unroll
            for (int p = 0; p < 3; p++)
#pragma unroll
                for (int nt = 0; nt < 4; nt++)
                    bn[p][nt] = *(const uint4*)(bt + p * W2P_STRIDE + (size_t)((kc + 1) * 4 + nt) * 1024);
        }

        uint4 au[3];
        cvt8(hv[2 * kc], hv[2 * kc + 1], au[0], au[1], au[2]);

#define GT_STEP(pa, pb)                                                     \
    {                                                                       \
        _Pragma("unroll")                                                   \
        for (int nt = 0; nt < 4; nt++)                                      \
            acc[nt] = __builtin_amdgcn_mfma_f32_16x16x32_bf16(              \
                as_bf(au[pa]), as_bf(bc[pb][nt]), acc[nt], 0, 0, 0);        \
    }
        PROD_SEQ(GT_STEP)
#undef GT_STEP

        if (kc + 1 < 8) {
#pragma unroll
            for (int p = 0; p < 3; p++)
#pragma unroll
                for (int nt = 0; nt < 4; nt++) bc[p][nt] = bn[p][nt];
        }
    }

    float b2v[4];
#pragma unroll
    for (int nt = 0; nt < 4; nt++) b2v[nt] = b2[nt * 16 + l15];

    // per r: lane holds 4 experts of token tok16 + lq*4 + r
#pragma unroll
    for (int r = 0; r < 4; r++) {
        float v[4]; int e[4];
#pragma unroll
        for (int nt = 0; nt < 4; nt++) { v[nt] = acc[nt][r] + b2v[nt]; e[nt] = nt * 16 + l15; }

        float a1 = v[0], a2 = v[1]; int j1 = e[0], j2 = e[1];
        if (v[1] > v[0]) { a1 = v[1]; j1 = e[1]; a2 = v[0]; j2 = e[0]; }
#pragma unroll
        for (int t = 2; t < 4; t++) {
            if (v[t] > a1) { a2 = a1; j2 = j1; a1 = v[t]; j1 = e[t]; }
            else if (v[t] > a2) { a2 = v[t]; j2 = e[t]; }
        }
#pragma unroll
        for (int off = 1; off < 16; off <<= 1) {
            float ob1 = __shfl_xor(a1, off, 64); int oj1 = __shfl_xor(j1, off, 64);
            float ob2 = __shfl_xor(a2, off, 64); int oj2 = __shfl_xor(j2, off, 64);
            bool bw = (ob1 > a1) || (ob1 == a1 && oj1 < j1);
            float w1v = bw ? ob1 : a1; int w1i = bw ? oj1 : j1;
            float lv = bw ? a1 : ob1;  int li  = bw ? j1 : oj1;
            float rv = bw ? ob2 : a2;  int ri  = bw ? oj2 : j2;
            bool cw = (lv > rv) || (lv == rv && li < ri);
            a1 = w1v; j1 = w1i;
            a2 = cw ? lv : rv; j2 = cw ? li : ri;
        }
        float ex = __expf(a2 - a1);
        float inv = 1.f / (1.f + ex);
        float g1 = inv, g2 = ex * inv;

        const size_t row = (size_t)(tok16 + lq * 4 + r) * NE;
#pragma unroll
        for (int nt = 0; nt < 4; nt++) {
            float gv = (e[nt] == j1) ? g1 : ((e[nt] == j2) ? g2 : 0.f);
            gates[row + e[nt]] = gv;
            logits_out[row + e[nt]] = v[nt];
        }
    }
}

extern "C" void kernel_launch(void* const* d_in, const int* in_sizes, int n_in,
                              void* d_out, int out_size, void* d_ws, size_t ws_size,
                              hipStream_t stream) {
    const float* x  = (const float*)d_in[0];
    const float* W1 = (const float*)d_in[1];
    const float* b1 = (const float*)d_in[2];
    const float* W2 = (const float*)d_in[3];
    const float* b2 = (const float*)d_in[4];

    const int T = in_sizes[0] / DM;   // 16384
    char* ws = (char*)d_ws;
    float* hbuf = (float*)(ws + H_OFF);
    float* gates  = (float*)d_out;
    float* logits = (float*)d_out + (size_t)T * NE;

    prep_planes<<<(131072 + 8192) / 256, 256, 0, stream>>>(W1, W2, ws);
    gemm1_mfma<<<dim3(T / BM, 2), 256, 0, stream>>>(x, ws + W1P_OFF, b1, hbuf);
    gate_kernel<<<T / 16, 64, 0, stream>>>(hbuf, ws + W2P_OFF, b2, gates, logits);
}

// Round 7
// 155.494 us; speedup vs baseline: 4.2243x; 1.1560x over previous
//
#include <hip/hip_runtime.h>
#include <math.h>

// SegmentGatingNetwork v5: f16 double-float MFMA (2 planes, 3 products) + fused GEMM2.
// x@W1: A staged via XOR-swizzled LDS dbuf, B(W1 f16 planes, scaled 2^11/2^23) from global
// in registers. preact = accP*2^-11 + accQ*2^-23 (exact pow2 folds). h -> LDS f16 planes ->
// in-block GEMM2 vs W2 planes -> partial logits (per 128-hid half) to LA/LB. finalize:
// logits = LA+LB+b2 (2 addends: deterministic), R1-verified top-2 butterfly + softmax.

#define DM 1024
#define DH 256
#define NE 64
#define BM 64
#define BN 128

// d_ws layout (bytes)
#define W1P_OFF 0                 // 2 planes x 524288 B (f16, fragment order, scaled)
#define W1P_STRIDE 524288
#define W2P_OFF 1048576           // 2 planes x 32768 B
#define W2P_STRIDE 32768
#define LA_OFF 1114112            // 16384*64*4 partial logits (hid 0..127)
#define LB_OFF 5308416            // partial logits (hid 128..255)

#define SWIZ(s) ((s) ^ (((s) >> 4) << 1))

typedef _Float16 f16x8 __attribute__((ext_vector_type(8)));
typedef __attribute__((ext_vector_type(4))) float f32x4;

__device__ __forceinline__ unsigned pk2(_Float16 a, _Float16 b) {
    union { _Float16 f; unsigned short u; } ca, cb;
    ca.f = a; cb.f = b;
    return (unsigned)ca.u | ((unsigned)cb.u << 16);   // low = even k, high = odd k
}

// split v into 2 f16 planes: v ~= ph + pm*2^-12  (RTN both; residual ~2^-22|v|)
__device__ __forceinline__ void cvt8(const float4& a, const float4& b, f16x8& ph, f16x8& pm) {
    float v[8] = {a.x, a.y, a.z, a.w, b.x, b.y, b.z, b.w};
#pragma unroll
    for (int j = 0; j < 8; j++) {
        _Float16 h = (_Float16)v[j];
        ph[j] = h;
        pm[j] = (_Float16)((v[j] - (float)h) * 4096.f);
    }
}

// ---------------- prep: weight f16 planes, fragment order, scaled by 2^11 ----------------
// plane dword idx = ((kc*NT + nt)*64 + L)*4 + q ; k0 = kc*32 + ((L>>4)&3)*8 + 2q ; n = nt*16+(L&15)
__global__ __launch_bounds__(256)
void prep_planes(const float* __restrict__ W1, const float* __restrict__ W2,
                 char* __restrict__ ws) {
    unsigned* w1p = (unsigned*)(ws + W1P_OFF);
    unsigned* w2p = (unsigned*)(ws + W2P_OFF);
    const int gt = blockIdx.x * 256 + threadIdx.x;
    if (gt < 131072) {   // W1: NT=16, kc<32
        const int q = gt & 3, L = (gt >> 2) & 63, nt = (gt >> 8) & 15, kc = gt >> 12;
        const int n = nt * 16 + (L & 15);
        const int k0 = kc * 32 + ((L >> 4) & 3) * 8 + 2 * q;
        float a0 = 2048.f * W1[(size_t)k0 * DH + n];
        float a1 = 2048.f * W1[(size_t)(k0 + 1) * DH + n];
        _Float16 h0 = (_Float16)a0, h1 = (_Float16)a1;
        _Float16 m0 = (_Float16)((a0 - (float)h0) * 4096.f);
        _Float16 m1 = (_Float16)((a1 - (float)h1) * 4096.f);
        w1p[gt] = pk2(h0, h1);
        w1p[131072 + gt] = pk2(m0, m1);
    } else if (gt < 139264) {   // W2: NT=4, kc<8
        const int g2 = gt - 131072;
        const int q = g2 & 3, L = (g2 >> 2) & 63, nt = (g2 >> 8) & 3, kc = g2 >> 10;
        const int n = nt * 16 + (L & 15);
        const int k0 = kc * 32 + ((L >> 4) & 3) * 8 + 2 * q;
        float a0 = 2048.f * W2[k0 * NE + n];
        float a1 = 2048.f * W2[(k0 + 1) * NE + n];
        _Float16 h0 = (_Float16)a0, h1 = (_Float16)a1;
        _Float16 m0 = (_Float16)((a0 - (float)h0) * 4096.f);
        _Float16 m1 = (_Float16)((a1 - (float)h1) * 4096.f);
        w2p[g2] = pk2(h0, h1);
        w2p[8192 + g2] = pk2(m0, m1);
    }
}

// ---------------- fused GEMM1 + partial GEMM2 ----------------
// block: 64 tok x 128 hid (y-half). 4 waves, wave tile 64 tok x 32 hid (ms=4, nt=2).
// grid (256, 2), 2 blocks/CU.
__global__ __launch_bounds__(256, 2)
void gemm1_fused(const float* __restrict__ x, const char* __restrict__ ws,
                 const float* __restrict__ b1, float* __restrict__ LA,
                 float* __restrict__ LB) {
    // [0,16384): A stage dbuf, 2 bufs x {plane p, ms} 8 x 1KB fragment blocks (XOR-swizzled)
    // epilogue overlay: h f16 planes, plane p at p*17408, row stride 272 B (64 rows x 128 k + pad)
    __shared__ __align__(16) char lds[34816];

    const int tid  = threadIdx.x;
    const int lane = tid & 63;
    const int wave = tid >> 6;       // hid group: n0 + wave*32
    const int l15  = lane & 15;
    const int lq   = lane >> 4;
    const int t0   = blockIdx.x * BM;
    const int yh   = blockIdx.y;
    const int n0   = yh * BN;

    // stager map: tok = tid>>2, kq = tid&3 (8 consecutive k per thread)
    const int stok = tid >> 2, skq = tid & 3;
    const float* xg = x + (size_t)(t0 + stok) * DM + skq * 8;
    const int sbase = ((stok >> 4) * 1024) + SWIZ(skq * 16 + (stok & 15)) * 16;
    const int rbase = SWIZ(lane) * 16;

    // B fragment base: frag id = kc*16 + (yh*8 + wave*2 + nt)
    const char* bt = ws + W1P_OFF + (size_t)(yh * 8 + wave * 2) * 1024 + lane * 16;

    f32x4 aP[4][2], aQ[4][2];
#pragma unroll
    for (int i = 0; i < 4; i++)
#pragma unroll
        for (int j = 0; j < 2; j++) {
            aP[i][j] = (f32x4){0.f, 0.f, 0.f, 0.f};
            aQ[i][j] = (f32x4){0.f, 0.f, 0.f, 0.f};
        }

    // prologue: stage kc=0, load B(kc=0)
    {
        float4 xa = *(const float4*)(xg);
        float4 xb = *(const float4*)(xg + 4);
        f16x8 ph, pm;
        cvt8(xa, xb, ph, pm);
        *(f16x8*)(lds + sbase) = ph;
        *(f16x8*)(lds + 4096 + sbase) = pm;
    }
    f16x8 bh[2], bm[2];
#pragma unroll
    for (int nt = 0; nt < 2; nt++) {
        bh[nt] = *(const f16x8*)(bt + nt * 1024);
        bm[nt] = *(const f16x8*)(bt + W1P_STRIDE + nt * 1024);
    }
    __syncthreads();

    for (int kc = 0; kc < 32; kc++) {
        const bool pre = (kc + 1) < 32;
        float4 xna, xnb;
        f16x8 bnh[2], bnm[2];
        if (pre) {
            xna = *(const float4*)(xg + (kc + 1) * 32);
            xnb = *(const float4*)(xg + (kc + 1) * 32 + 4);
            const char* btn = bt + (size_t)(kc + 1) * 16384;
#pragma unroll
            for (int nt = 0; nt < 2; nt++) {
                bnh[nt] = *(const f16x8*)(btn + nt * 1024);
                bnm[nt] = *(const f16x8*)(btn + W1P_STRIDE + nt * 1024);
            }
        }

        // A fragments from LDS
        const char* ab = lds + (kc & 1) * 8192 + rbase;
        f16x8 ah[4], am[4];
#pragma unroll
        for (int ms = 0; ms < 4; ms++) {
            ah[ms] = *(const f16x8*)(ab + ms * 1024);
            am[ms] = *(const f16x8*)(ab + (4 + ms) * 1024);
        }

        // 3 products: P += hh ; Q += h*m + m*h
#pragma unroll
        for (int ms = 0; ms < 4; ms++)
#pragma unroll
            for (int nt = 0; nt < 2; nt++)
                aP[ms][nt] = __builtin_amdgcn_mfma_f32_16x16x32_f16(ah[ms], bh[nt], aP[ms][nt], 0, 0, 0);
#pragma unroll
        for (int ms = 0; ms < 4; ms++)
#pragma unroll
            for (int nt = 0; nt < 2; nt++) {
                aQ[ms][nt] = __builtin_amdgcn_mfma_f32_16x16x32_f16(ah[ms], bm[nt], aQ[ms][nt], 0, 0, 0);
                aQ[ms][nt] = __builtin_amdgcn_mfma_f32_16x16x32_f16(am[ms], bh[nt], aQ[ms][nt], 0, 0, 0);
            }

        if (pre) {
            f16x8 ph, pm;
            cvt8(xna, xnb, ph, pm);
            char* d = lds + ((kc + 1) & 1) * 8192 + sbase;
            *(f16x8*)(d) = ph;
            *(f16x8*)(d + 4096) = pm;
#pragma unroll
            for (int nt = 0; nt < 2; nt++) { bh[nt] = bnh[nt]; bm[nt] = bnm[nt]; }
        }
        __syncthreads();
    }

    // ---- epilogue A: h = tanh(aP*2^-11 + aQ*2^-23 + b1) -> LDS f16 planes ----
    const float c1 = 0x1p-11f, c2 = 0x1p-23f;
#pragma unroll
    for (int nt = 0; nt < 2; nt++) {
        const int kl = wave * 32 + nt * 16 + l15;        // local hid 0..127
        const float bias = b1[n0 + kl];
#pragma unroll
        for (int ms = 0; ms < 4; ms++) {
#pragma unroll
            for (int r = 0; r < 4; r++) {
                const int tok = ms * 16 + lq * 4 + r;    // local token (C/D layout)
                float hv = tanhf(aP[ms][nt][r] * c1 + aQ[ms][nt][r] * c2 + bias);
                _Float16 hh = (_Float16)hv;
                _Float16 hm = (_Float16)((hv - (float)hh) * 4096.f);
                *(_Float16*)(lds + tok * 272 + kl * 2) = hh;
                *(_Float16*)(lds + 17408 + tok * 272 + kl * 2) = hm;
            }
        }
    }
    __syncthreads();

    // ---- epilogue B: partial logits = h-tile @ W2(local 128 k) -> LA/LB ----
    // wave handles tok rows wave*16..+15, all 64 experts.
    const char* w2b = ws + W2P_OFF + lane * 16;
    f32x4 qP[4], qQ[4];
#pragma unroll
    for (int nt = 0; nt < 4; nt++) {
        qP[nt] = (f32x4){0.f, 0.f, 0.f, 0.f};
        qQ[nt] = (f32x4){0.f, 0.f, 0.f, 0.f};
    }
#pragma unroll
    for (int kf = 0; kf < 4; kf++) {
        const char* hb = lds + (wave * 16 + l15) * 272 + (kf * 32 + lq * 8) * 2;
        f16x8 ah2 = *(const f16x8*)(hb);
        f16x8 am2 = *(const f16x8*)(hb + 17408);
        const int fb = (yh * 4 + kf) * 4;
#pragma unroll
        for (int nt = 0; nt < 4; nt++) {
            f16x8 wbh = *(const f16x8*)(w2b + (size_t)(fb + nt) * 1024);
            f16x8 wbm = *(const f16x8*)(w2b + W2P_STRIDE + (size_t)(fb + nt) * 1024);
            qP[nt] = __builtin_amdgcn_mfma_f32_16x16x32_f16(ah2, wbh, qP[nt], 0, 0, 0);
            qQ[nt] = __builtin_amdgcn_mfma_f32_16x16x32_f16(ah2, wbm, qQ[nt], 0, 0, 0);
            qQ[nt] = __builtin_amdgcn_mfma_f32_16x16x32_f16(am2, wbh, qQ[nt], 0, 0, 0);
        }
    }
    float* po = yh ? LB : LA;
#pragma unroll
    for (int nt = 0; nt < 4; nt++)
#pragma unroll
        for (int r = 0; r < 4; r++) {
            const int tok = wave * 16 + lq * 4 + r;
            po[(size_t)(t0 + tok) * NE + nt * 16 + l15] = qP[nt][r] * c1 + qQ[nt][r] * c2;
        }
}

// ---------------- finalize: logits = LA + LB + b2; top-2 softmax scatter ----------------
__global__ __launch_bounds__(256)
void finalize_gate(const float* __restrict__ LA, const float* __restrict__ LB,
                   const float* __restrict__ b2, float* __restrict__ gates,
                   float* __restrict__ logits_out) {
    const int tid = threadIdx.x;
    const int wave = tid >> 6;
    const int lane = tid & 63;
    const int t0 = blockIdx.x * 64;
    const float b2v = b2[lane];

#pragma unroll 1
    for (int t = 0; t < 16; t++) {
        const int tok = t0 + wave * 16 + t;
        const size_t row = (size_t)tok * NE;
        const float lg = LA[row + lane] + LB[row + lane] + b2v;

        // top-1 (lower index wins ties, matching jax.lax.top_k)
        float m1 = lg; int i1 = lane;
#pragma unroll
        for (int off = 32; off; off >>= 1) {
            float om = __shfl_xor(m1, off, 64);
            int oi = __shfl_xor(i1, off, 64);
            if (om > m1 || (om == m1 && oi < i1)) { m1 = om; i1 = oi; }
        }
        // top-2
        float l2 = (lane == i1) ? -INFINITY : lg;
        float m2 = l2; int i2 = lane;
#pragma unroll
        for (int off = 32; off; off >>= 1) {
            float om = __shfl_xor(m2, off, 64);
            int oi = __shfl_xor(i2, off, 64);
            if (om > m2 || (om == m2 && oi < i2)) { m2 = om; i2 = oi; }
        }
        float e = __expf(m2 - m1);
        float inv = 1.f / (1.f + e);
        float g = (lane == i1) ? inv : ((lane == i2) ? e * inv : 0.f);
        gates[row + lane] = g;
        logits_out[row + lane] = lg;
    }
}

extern "C" void kernel_launch(void* const* d_in, const int* in_sizes, int n_in,
                              void* d_out, int out_size, void* d_ws, size_t ws_size,
                              hipStream_t stream) {
    const float* x  = (const float*)d_in[0];
    const float* W1 = (const float*)d_in[1];
    const float* b1 = (const float*)d_in[2];
    const float* W2 = (const float*)d_in[3];
    const float* b2 = (const float*)d_in[4];

    const int T = in_sizes[0] / DM;   // 16384
    char* ws = (char*)d_ws;
    float* LA = (float*)(ws + LA_OFF);
    float* LB = (float*)(ws + LB_OFF);
    float* gates  = (float*)d_out;
    float* logits = (float*)d_out + (size_t)T * NE;

    prep_planes<<<544, 256, 0, stream>>>(W1, W2, ws);
    gemm1_fused<<<dim3(T / BM, 2), 256, 0, stream>>>(x, ws, b1, LA, LB);
    finalize_gate<<<T / 64, 256, 0, stream>>>(LA, LB, b2, gates, logits);
}